// Round 10
// baseline (224.142 us; speedup 1.0000x reference)
//
#include <hip/hip_runtime.h>

// ---- fused front-end v4: v2 structure + register-prefetch software pipeline ----
// 8x8 px tile, 1024 blocks (4/CU). wave = full tile (lane=px).
// Per 16-ch chunk: write prefetched halo -> LDS -> prefetch NEXT chunk (overlaps
// compute) -> wave w dw-convs its 4 channels -> pw 16w..16w+15, red 4w..4w+3.
__launch_bounds__(256, 4)
__global__ void k_front(const float* __restrict__ in, const float* __restrict__ wdw,
                        const float* __restrict__ wpw, const float* __restrict__ wred,
                        float* __restrict__ h, float* __restrict__ r,
                        float* __restrict__ stats){
  __shared__ float4 s_in4[4][10][12];                // [c4][ry][rx] 4ch contiguous
  __shared__ float4 s_dw4[4][64];                    // [c4][px]
  __shared__ float  s_red[4][8];
  int t = threadIdx.x;
  int w = t >> 6, lane = t & 63;
  int lx = lane & 7, ly = lane >> 3;
  int tile = blockIdx.x & 255, b = blockIdx.x >> 8;
  int x0 = (tile & 15) << 3, y0 = (tile >> 4) << 3;
  const float* inb = in + ((long)b << 20);

  // staging split: i = c4*100 + ry*10 + rx; thread handles i0=t and i1=t+256
  int c4a = t / 100, pa = t - c4a * 100;
  int rya = pa / 10, rxa = pa - rya * 10;
  int ya = y0 + rya - 1, xa = x0 + rxa - 1;
  bool oka = (unsigned)ya < 128u && (unsigned)xa < 128u;
  long offa = ((long)(c4a << 2) << 14) + (ya << 7) + xa;
  int i1 = t + 256;
  int c4b = i1 / 100, pb = i1 - c4b * 100;
  int ryb = pb / 10, rxb = pb - ryb * 10;
  int yb = y0 + ryb - 1, xb = x0 + rxb - 1;
  bool okb = (i1 < 400) && (unsigned)yb < 128u && (unsigned)xb < 128u;
  long offb = ((long)(c4b << 2) << 14) + (yb << 7) + xb;

  float4 A, B;
  auto ldchunk = [&](int c0){
    A = make_float4(0.f, 0.f, 0.f, 0.f);
    B = make_float4(0.f, 0.f, 0.f, 0.f);
    if (oka){
      long o = offa + ((long)c0 << 14);
      A.x = inb[o]; A.y = inb[o + 16384]; A.z = inb[o + 32768]; A.w = inb[o + 49152];
    }
    if (okb){
      long o = offb + ((long)c0 << 14);
      B.x = inb[o]; B.y = inb[o + 16384]; B.z = inb[o + 32768]; B.w = inb[o + 49152];
    }
  };

  float pacc[16], racc[4];
  #pragma unroll
  for (int j = 0; j < 16; j++) pacc[j] = 0.f;
  #pragma unroll
  for (int j = 0; j < 4; j++) racc[j] = 0.f;

  ldchunk(0);                                        // prefetch chunk 0
  for (int q = 0; q < 4; q++){
    int c0 = q << 4;
    if (q) __syncthreads();                          // s_in4/s_dw4 free
    s_in4[c4a][rya][rxa] = A;
    if (i1 < 400) s_in4[c4b][ryb][rxb] = B;
    __syncthreads();
    if (q < 3) ldchunk(c0 + 16);                     // prefetch next: overlaps below

    // dw: wave w convolves its 4 channels (c0+4w..+3), once per px
    {
      const float* wd = wdw + (c0 + (w << 2)) * 9;   // uniform -> s_load
      float4 a = make_float4(0.f, 0.f, 0.f, 0.f);
      #pragma unroll
      for (int dy = 0; dy < 3; dy++){
        #pragma unroll
        for (int dx = 0; dx < 3; dx++){
          float4 v = s_in4[w][ly + dy][lx + dx];
          int k = dy * 3 + dx;
          a.x += v.x * wd[k];
          a.y += v.y * wd[9 + k];
          a.z += v.z * wd[18 + k];
          a.w += v.w * wd[27 + k];
        }
      }
      s_dw4[w][lane] = a;
    }
    __syncthreads();

    // pw + red over the chunk's 4 c4-groups
    #pragma unroll
    for (int g = 0; g < 4; g++){
      float4 d  = s_dw4[g][lane];
      float4 cv = s_in4[g][ly + 1][lx + 1];          // raw center for reduce
      int cc = c0 + (g << 2);
      #pragma unroll
      for (int j = 0; j < 16; j++){
        const float* wr = wpw + ((w << 4) + j) * 64 + cc;  // uniform -> s_load
        pacc[j] += d.x * wr[0] + d.y * wr[1] + d.z * wr[2] + d.w * wr[3];
      }
      #pragma unroll
      for (int j = 0; j < 4; j++){
        const float* wr = wred + ((w << 2) + j) * 64 + cc;
        racc[j] += cv.x * wr[0] + cv.y * wr[1] + cv.z * wr[2] + cv.w * wr[3];
      }
    }
  }

  long sp = ((long)(y0 + ly) << 7) + x0 + lx;
  float* hb = h + ((long)b << 20) + sp;
  #pragma unroll
  for (int j = 0; j < 16; j++) hb[(long)((w << 4) + j) << 14] = pacc[j];
  float* rb = r + ((long)b << 18) + sp;
  #pragma unroll
  for (int j = 0; j < 4; j++) rb[(long)((w << 2) + j) << 14] = racc[j];

  // BN stats: wave w owns channels 4w..4w+3
  #pragma unroll
  for (int j = 0; j < 4; j++){
    float v = racc[j], s2 = racc[j] * racc[j];
    #pragma unroll
    for (int off = 32; off > 0; off >>= 1){
      v  += __shfl_down(v,  off, 64);
      s2 += __shfl_down(s2, off, 64);
    }
    if (lane == 0){ s_red[w][2 * j] = v; s_red[w][2 * j + 1] = s2; }
  }
  __syncthreads();
  if (t < 32) atomicAdd(&stats[t], s_red[t >> 3][t & 7]);
}

// ---- main involution: per (b, g, 16x16 tile); BN finalize folded in ----
__launch_bounds__(256)
__global__ void k_main(const float* __restrict__ h, const float* __restrict__ r,
                       const float* __restrict__ stats, const float* __restrict__ gamma,
                       const float* __restrict__ beta, const float* __restrict__ wspan,
                       float* __restrict__ out){
  __shared__ float4 s_h4[22][24];                    // [row][col] -> 4 cg contiguous
  int t = threadIdx.x;
  int g = blockIdx.y, b = blockIdx.z;
  int tx0 = (blockIdx.x & 7) << 4, ty0 = (blockIdx.x >> 3) << 4;

  const float* hp = h + (((long)(b * 64 + g * 4)) << 14);
  for (int p = t; p < 484; p += 256){                // 22x22 halo points
    int ry = p / 22, rx = p - ry * 22;
    int yy = ty0 + ry - 3, xx = tx0 + rx - 3;
    float4 v = make_float4(0.f, 0.f, 0.f, 0.f);
    if ((unsigned)yy < 128u && (unsigned)xx < 128u){
      int o = (yy << 7) + xx;
      v.x = hp[o];
      v.y = hp[o + 16384];
      v.z = hp[o + 32768];
      v.w = hp[o + 49152];
    }
    s_h4[ry][rx] = v;
  }

  int ltx = t & 15, lty = t >> 4;
  int px = tx0 + ltx, py = ty0 + lty;
  const float* rp = r + ((long)b << 18) + (py << 7) + px;
  const float inv_n = 1.f / 65536.f;                 // 1/(B*H*W)
  float rv[16];
  #pragma unroll
  for (int c = 0; c < 16; c++){
    float mean = stats[2 * c] * inv_n;
    float var  = stats[2 * c + 1] * inv_n - mean * mean;
    float sc   = gamma[c] * rsqrtf(var + 1e-5f);
    float bi   = beta[c] - mean * sc;
    float v = rp[(long)c << 14];
    rv[c] = fmaxf(v * sc + bi, 0.f);
  }
  __syncthreads();

  // fused kern-gen + conv; kv split into 2 chains to break FMA dependency
  const float* wsp = wspan + g * 784;                // uniform -> scalar pipe
  float acc0 = 0.f, acc1 = 0.f, acc2 = 0.f, acc3 = 0.f;
  #pragma unroll
  for (int kh = 0; kh < 7; kh++){
    #pragma unroll
    for (int kw = 0; kw < 7; kw++){
      int k = kh * 7 + kw;
      float kv0 = 0.f, kv1 = 0.f;
      #pragma unroll
      for (int c = 0; c < 16; c += 2){
        kv0 += rv[c]     * wsp[k * 16 + c];
        kv1 += rv[c + 1] * wsp[k * 16 + c + 1];
      }
      float kv = kv0 + kv1;
      float4 hv = s_h4[lty + kh][ltx + kw];
      acc0 += kv * hv.x;
      acc1 += kv * hv.y;
      acc2 += kv * hv.z;
      acc3 += kv * hv.w;
    }
  }

  long obase = (((long)(b * 64 + g * 4)) << 14) + (py << 7) + px;
  out[obase]         = acc0;
  out[obase + 16384] = acc1;
  out[obase + 32768] = acc2;
  out[obase + 49152] = acc3;
}

extern "C" void kernel_launch(void* const* d_in, const int* in_sizes, int n_in,
                              void* d_out, int out_size, void* d_ws, size_t ws_size,
                              hipStream_t stream){
  const float* in       = (const float*)d_in[0];
  const float* w_dw     = (const float*)d_in[1];
  const float* w_pw     = (const float*)d_in[2];
  const float* gamma    = (const float*)d_in[3];
  const float* beta     = (const float*)d_in[4];
  const float* w_reduce = (const float*)d_in[5];
  const float* w_span   = (const float*)d_in[6];
  float* out = (float*)d_out;

  float* ws    = (float*)d_ws;
  float* h     = ws;                    // 4194304 floats
  float* r     = ws + 4194304;          // 1048576 floats
  float* stats = ws + 5242880;          // 32 floats

  hipMemsetAsync(stats, 0, 32 * sizeof(float), stream);
  k_front<<<1024, 256, 0, stream>>>(in, w_dw, w_pw, w_reduce, h, r, stats);
  dim3 grid(64, 16, 4);
  k_main <<<grid, 256, 0, stream>>>(h, r, stats, gamma, beta, w_span, out);
}

// Round 11
// 171.772 us; speedup vs baseline: 1.3049x; 1.3049x over previous
//
#include <hip/hip_runtime.h>

// ---- fused front-end v2 (proven 61.5us twice, VGPR 52 — DO NOT add registers) ----
// 8x8 px tile, 1024 blocks (4/CU). wave = full tile (lane=px).
__launch_bounds__(256, 4)
__global__ void k_front(const float* __restrict__ in, const float* __restrict__ wdw,
                        const float* __restrict__ wpw, const float* __restrict__ wred,
                        float* __restrict__ h, float* __restrict__ r,
                        float* __restrict__ stats){
  __shared__ float4 s_in4[4][10][12];                // [c4][ry][rx] 4ch contiguous
  __shared__ float4 s_dw4[4][64];                    // [c4][px]
  __shared__ float4 s_cv4[4][64];                    // [c4][px] raw center vals
  __shared__ float  s_red[4][8];
  int t = threadIdx.x;
  int w = t >> 6, lane = t & 63;
  int lx = lane & 7, ly = lane >> 3;
  int blk = blockIdx.x;
  int tile = blk & 255, b = blk >> 8;
  int x0 = (tile & 15) << 3, y0 = (tile >> 4) << 3;
  const float* inb = in + ((long)b << 20);

  float pacc[16], racc[4];
  #pragma unroll
  for (int j = 0; j < 16; j++) pacc[j] = 0.f;
  #pragma unroll
  for (int j = 0; j < 4; j++) racc[j] = 0.f;

  for (int q = 0; q < 4; q++){
    int c0 = q << 4;
    __syncthreads();                                 // s_in4 free (prev dw done)
    for (int i = t; i < 400; i += 256){              // 4 c4-groups x 10x10 halo
      int c4 = i / 100, pos = i - c4 * 100;
      int ry = pos / 10, rx = pos - ry * 10;
      int yy = y0 + ry - 1, xx = x0 + rx - 1;
      float4 v = make_float4(0.f, 0.f, 0.f, 0.f);
      if ((unsigned)yy < 128u && (unsigned)xx < 128u){
        long base = ((long)(c0 + (c4 << 2)) << 14) + (yy << 7) + xx;
        v.x = inb[base];
        v.y = inb[base + 16384];
        v.z = inb[base + 32768];
        v.w = inb[base + 49152];
      }
      s_in4[c4][ry][rx] = v;
    }
    __syncthreads();

    // dw: wave w convolves its 4 channels (c0+4w .. +3), once per px
    {
      const float* wd = wdw + (c0 + (w << 2)) * 9;   // uniform -> s_load
      float4 a = make_float4(0.f, 0.f, 0.f, 0.f);
      float4 cv = make_float4(0.f, 0.f, 0.f, 0.f);
      #pragma unroll
      for (int dy = 0; dy < 3; dy++){
        #pragma unroll
        for (int dx = 0; dx < 3; dx++){
          float4 v = s_in4[w][ly + dy][lx + dx];
          int k = dy * 3 + dx;
          a.x += v.x * wd[k];
          a.y += v.y * wd[9 + k];
          a.z += v.z * wd[18 + k];
          a.w += v.w * wd[27 + k];
          if (k == 4) cv = v;
        }
      }
      s_dw4[w][lane] = a;
      s_cv4[w][lane] = cv;
    }
    __syncthreads();

    float4 d0 = s_dw4[0][lane], d1 = s_dw4[1][lane];
    float4 d2 = s_dw4[2][lane], d3 = s_dw4[3][lane];
    float4 e0 = s_cv4[0][lane], e1 = s_cv4[1][lane];
    float4 e2 = s_cv4[2][lane], e3 = s_cv4[3][lane];
    #pragma unroll
    for (int j = 0; j < 16; j++){
      const float* wr = wpw + ((w << 4) + j) * 64 + c0;  // uniform -> s_load
      float s = pacc[j];
      s += d0.x * wr[0]  + d0.y * wr[1]  + d0.z * wr[2]  + d0.w * wr[3];
      s += d1.x * wr[4]  + d1.y * wr[5]  + d1.z * wr[6]  + d1.w * wr[7];
      s += d2.x * wr[8]  + d2.y * wr[9]  + d2.z * wr[10] + d2.w * wr[11];
      s += d3.x * wr[12] + d3.y * wr[13] + d3.z * wr[14] + d3.w * wr[15];
      pacc[j] = s;
    }
    #pragma unroll
    for (int j = 0; j < 4; j++){
      const float* wr = wred + ((w << 2) + j) * 64 + c0;
      float s = racc[j];
      s += e0.x * wr[0]  + e0.y * wr[1]  + e0.z * wr[2]  + e0.w * wr[3];
      s += e1.x * wr[4]  + e1.y * wr[5]  + e1.z * wr[6]  + e1.w * wr[7];
      s += e2.x * wr[8]  + e2.y * wr[9]  + e2.z * wr[10] + e2.w * wr[11];
      s += e3.x * wr[12] + e3.y * wr[13] + e3.z * wr[14] + e3.w * wr[15];
      racc[j] = s;
    }
  }

  long sp = ((long)(y0 + ly) << 7) + x0 + lx;
  float* hb = h + ((long)b << 20) + sp;
  #pragma unroll
  for (int j = 0; j < 16; j++) hb[(long)((w << 4) + j) << 14] = pacc[j];
  float* rb = r + ((long)b << 18) + sp;
  #pragma unroll
  for (int j = 0; j < 4; j++) rb[(long)((w << 2) + j) << 14] = racc[j];

  // BN stats: wave w owns channels 4w..4w+3
  #pragma unroll
  for (int j = 0; j < 4; j++){
    float v = racc[j], s2 = racc[j] * racc[j];
    #pragma unroll
    for (int off = 32; off > 0; off >>= 1){
      v  += __shfl_down(v,  off, 64);
      s2 += __shfl_down(s2, off, 64);
    }
    if (lane == 0){ s_red[w][2 * j] = v; s_red[w][2 * j + 1] = s2; }
  }
  __syncthreads();
  if (t < 32) atomicAdd(&stats[t], s_red[t >> 3][t & 7]);
}

// ---- main involution: per (b, g, 16x16 tile) ----
// BN finalize folded in; w_span staged in LDS -> ds_read_b128 broadcast
// (defeats the SGPR-starved s_load refill serialization: SGPR_Count=48
//  cannot hold 784 weights, so scalar-pipe reloads stalled the FMA loop)
__launch_bounds__(256)
__global__ void k_main(const float* __restrict__ h, const float* __restrict__ r,
                       const float* __restrict__ stats, const float* __restrict__ gamma,
                       const float* __restrict__ beta, const float* __restrict__ wspan,
                       float* __restrict__ out){
  __shared__ float4 s_h4[22][24];                    // [row][col] -> 4 cg contiguous
  __shared__ float4 s_w[196];                        // 49 taps x 4 float4 = 784 w
  int t = threadIdx.x;
  int g = blockIdx.y, b = blockIdx.z;
  int tx0 = (blockIdx.x & 7) << 4, ty0 = (blockIdx.x >> 3) << 4;

  // stage w_span tile (coalesced, divergent addr -> guaranteed vector loads)
  const float4* wsp4 = (const float4*)(wspan + g * 784);
  if (t < 196) s_w[t] = wsp4[t];

  const float* hp = h + (((long)(b * 64 + g * 4)) << 14);
  for (int p = t; p < 484; p += 256){                // 22x22 halo points
    int ry = p / 22, rx = p - ry * 22;
    int yy = ty0 + ry - 3, xx = tx0 + rx - 3;
    float4 v = make_float4(0.f, 0.f, 0.f, 0.f);
    if ((unsigned)yy < 128u && (unsigned)xx < 128u){
      int o = (yy << 7) + xx;
      v.x = hp[o];
      v.y = hp[o + 16384];
      v.z = hp[o + 32768];
      v.w = hp[o + 49152];
    }
    s_h4[ry][rx] = v;
  }

  int ltx = t & 15, lty = t >> 4;
  const float* rp = r + ((long)b << 18) + ((long)(ty0 + lty) << 7) + tx0 + ltx;
  const float inv_n = 1.f / 65536.f;                 // 1/(B*H*W)
  float4 rv4[4];
  #pragma unroll
  for (int c4 = 0; c4 < 4; c4++){
    float tmp[4];
    #pragma unroll
    for (int j = 0; j < 4; j++){
      int c = (c4 << 2) + j;
      float mean = stats[2 * c] * inv_n;             // uniform -> s_load (tiny)
      float var  = stats[2 * c + 1] * inv_n - mean * mean;
      float sc   = gamma[c] * rsqrtf(var + 1e-5f);
      float bi   = beta[c] - mean * sc;
      tmp[j] = fmaxf(rp[(long)c << 14] * sc + bi, 0.f);
    }
    rv4[c4] = make_float4(tmp[0], tmp[1], tmp[2], tmp[3]);
  }
  __syncthreads();

  // fused kern-gen + conv: per tap 4x ds_read_b128(broadcast) + 16 FMA + 1 b128 + 4 FMA
  float acc0 = 0.f, acc1 = 0.f, acc2 = 0.f, acc3 = 0.f;
  #pragma unroll
  for (int kh = 0; kh < 7; kh++){
    #pragma unroll
    for (int kw = 0; kw < 7; kw++){
      int k = kh * 7 + kw;
      float4 w0 = s_w[(k << 2)],     w1 = s_w[(k << 2) + 1];
      float4 w2 = s_w[(k << 2) + 2], w3 = s_w[(k << 2) + 3];
      float kv0 = rv4[0].x * w0.x + rv4[0].y * w0.y + rv4[0].z * w0.z + rv4[0].w * w0.w
                + rv4[1].x * w1.x + rv4[1].y * w1.y + rv4[1].z * w1.z + rv4[1].w * w1.w;
      float kv1 = rv4[2].x * w2.x + rv4[2].y * w2.y + rv4[2].z * w2.z + rv4[2].w * w2.w
                + rv4[3].x * w3.x + rv4[3].y * w3.y + rv4[3].z * w3.z + rv4[3].w * w3.w;
      float kv = kv0 + kv1;
      float4 hv = s_h4[lty + kh][ltx + kw];
      acc0 += kv * hv.x;
      acc1 += kv * hv.y;
      acc2 += kv * hv.z;
      acc3 += kv * hv.w;
    }
  }

  long obase = (((long)(b * 64 + g * 4)) << 14) + ((long)(ty0 + lty) << 7) + tx0 + ltx;
  out[obase]         = acc0;
  out[obase + 16384] = acc1;
  out[obase + 32768] = acc2;
  out[obase + 49152] = acc3;
}

extern "C" void kernel_launch(void* const* d_in, const int* in_sizes, int n_in,
                              void* d_out, int out_size, void* d_ws, size_t ws_size,
                              hipStream_t stream){
  const float* in       = (const float*)d_in[0];
  const float* w_dw     = (const float*)d_in[1];
  const float* w_pw     = (const float*)d_in[2];
  const float* gamma    = (const float*)d_in[3];
  const float* beta     = (const float*)d_in[4];
  const float* w_reduce = (const float*)d_in[5];
  const float* w_span   = (const float*)d_in[6];
  float* out = (float*)d_out;

  float* ws    = (float*)d_ws;
  float* h     = ws;                    // 4194304 floats
  float* r     = ws + 4194304;          // 1048576 floats
  float* stats = ws + 5242880;          // 32 floats

  hipMemsetAsync(stats, 0, 32 * sizeof(float), stream);
  k_front<<<1024, 256, 0, stream>>>(in, w_dw, w_pw, w_reduce, h, r, stats);
  dim3 grid(64, 16, 4);
  k_main <<<grid, 256, 0, stream>>>(h, r, stats, gamma, beta, w_span, out);
}